// Round 10
// baseline (153.010 us; speedup 1.0000x reference)
//
#include <hip/hip_runtime.h>
#include <hip/hip_fp16.h>

#define PP 9216   // 96*96 pixels per batch

typedef _Float16 f16x8 __attribute__((ext_vector_type(8)));
typedef _Float16 f16x4 __attribute__((ext_vector_type(4)));
typedef _Float16 h2    __attribute__((ext_vector_type(2)));
typedef float    f32x4 __attribute__((ext_vector_type(4)));

// LDS 20480 B; with launch_bounds(256,6): 6 blocks/CU -> 1536 capacity,
// whole 1152-block grid resident in one round.
//  0..16384   sXK[64][128] swz128: X (P1..P2-read) -> K written IN PLACE per
//             16-row stripe (P2) -> after B2.5 (QK^T done):
//               0..8192     sP 4 x 2048B head slabs [16 px][64 pos] swz64
//               8192..16384 sV 4 x 2048B wave slabs [32 d][32 pos] swz32,
//                           staged TWICE (positions 0-31 then 32-63)
//  16384..20480  sQ[16][128] swz128 -> sAo (PV..proj)
#define LDS_BYTES 20480

// swizzled half-index within a 128-half (256B, 16x16B-chunk) row
__device__ __forceinline__ int swz128(int row, int hc) {
    return row * 128 + (((hc >> 3) ^ (row & 15)) << 3) + (hc & 7);
}
// swizzled half-index within a 64-half (128B, 8x16B-chunk) row
__device__ __forceinline__ int swz64(int row, int hc) {
    return row * 64 + (((hc >> 3) ^ (row & 7)) << 3) + (hc & 7);
}
// swizzled half-index within a 32-half (64B, 4x16B-chunk) row
__device__ __forceinline__ int swz32(int row, int hc) {
    return row * 32 + (((hc >> 3) ^ (row & 3)) << 3) + (hc & 7);
}

// ---------------------------------------------------------------------------
// prep_w: one-time f32 -> f16 weight conversion.
// wqkv16[o][c], o in [0,384): 0-127 wq, 128-255 wk, 256-383 wv. wp16[c][o].
// ---------------------------------------------------------------------------
__global__ __launch_bounds__(256) void prep_w(
    const float* __restrict__ wq, const float* __restrict__ wk,
    const float* __restrict__ wv, const float* __restrict__ wp,
    _Float16* __restrict__ wqkv16, _Float16* __restrict__ wp16)
{
    int e = (blockIdx.x * 256 + threadIdx.x) * 4;   // 4 elems/thread, 65536 total
    const float* src;
    _Float16* dst;
    if (e < 49152) {
        int o = e >> 7;
        src = (o < 128) ? (wq + (size_t)o * 128)
            : (o < 256) ? (wk + (size_t)(o - 128) * 128)
                        : (wv + (size_t)(o - 256) * 128);
        src += (e & 127);
        dst = wqkv16 + e;
    } else {
        int j = e - 49152;
        src = wp + j;
        dst = wp16 + j;
    }
    float4 v = *(const float4*)src;
    f16x4 h;
    h[0] = (_Float16)v.x; h[1] = (_Float16)v.y;
    h[2] = (_Float16)v.z; h[3] = (_Float16)v.w;
    *(f16x4*)dst = h;
}

// ---------------------------------------------------------------------------
// Fully fused window self-attention, 4x4 px tile (8x8 halo), 4 waves,
// wave w owns head w. launch_bounds(256,6): VGPR cap ~85 (measured need 64,
// no spill) and 6 blocks/CU -> full-grid residency. K overwrites X in place
// (stripe-synchronized). V^T staged in two 2KB half-slabs.
// ---------------------------------------------------------------------------
__global__ __launch_bounds__(256, 6) void fused_attn(
    const float* __restrict__ x, const _Float16* __restrict__ wqkv,
    const _Float16* __restrict__ wp16, float* __restrict__ out)
{
    __shared__ __align__(16) char smem[LDS_BYTES];
    _Float16* sXK = (_Float16*)smem;             // X -> K (in place) -> sP+sV
    _Float16* sQ  = (_Float16*)(smem + 16384);   // Q -> sAo

    const int t = threadIdx.x;
    const int w = t >> 6, lane = t & 63, lm = lane & 15, quad = lane >> 4;

    // XCD-bijective swizzle: 1152 = 8 XCDs x 144 contiguous blocks
    const int wgid = (blockIdx.x & 7) * 144 + (blockIdx.x >> 3);
    const int b = wgid / 576;
    const int rem = wgid - b * 576;
    const int x0 = (rem % 24) * 4, y0 = (rem / 24) * 4;

    const float* xb = x + (size_t)b * 128 * PP;
    float* ob = out + (size_t)b * 128 * PP;

    // ---- hold K/V weight fragments in registers (issued first; latency
    // overlaps P1). ni 0,1 -> K N-tiles {w,w+4}; ni 2,3 -> V tiles {2w,2w+1}.
    f16x8 BKV[4][4];
    #pragma unroll
    for (int ni = 0; ni < 4; ni++) {
        const int wrow = (ni < 2) ? (128 + (w + 4 * ni) * 16 + lm)
                                  : (256 + (2 * w + (ni - 2)) * 16 + lm);
        const _Float16* wr = wqkv + (size_t)wrow * 128;
        #pragma unroll
        for (int kc = 0; kc < 4; kc++)
            BKV[ni][kc] = *(const f16x8*)(wr + kc * 32 + quad * 8);
    }

    // ---- P1: stage 8x8 halo x 128ch, f32 -> f16 transposed into sXK[pos][c].
    // Two batches of 8 float2 (halves register hold vs R9's 16).
    {
        const int pos = (t & 31) * 2;
        const int gy = y0 - 2 + (pos >> 3);
        const int gx = x0 - 2 + (pos & 7);         // even; float2 never straddles
        const bool inb = ((unsigned)gy < 96u) && ((unsigned)gx < 96u);
        const float* src = xb + (size_t)(t >> 5) * PP + gy * 96 + gx;
        #pragma unroll
        for (int g = 0; g < 2; g++) {
            float2 vv[8];
            #pragma unroll
            for (int i = 0; i < 8; i++)
                vv[i] = inb ? *(const float2*)(src + (size_t)((g * 8 + i) * 8) * PP)
                            : make_float2(0.f, 0.f);
            #pragma unroll
            for (int i = 0; i < 8; i++) {
                int c = (g * 8 + i) * 8 + (t >> 5);
                sXK[swz128(pos,     c)] = (_Float16)vv[i].x;
                sXK[swz128(pos + 1, c)] = (_Float16)vv[i].y;
            }
        }
    }
    __syncthreads();                      // B1: sX ready

    // ---- P3a: A-frags for Q (interior halo rows 18..45) BEFORE the in-place
    // K writes destroy them (stripe m=1 overwrites rows 16..31).
    f16x8 A3[4];
    {
        int hrow = ((lm >> 2) + 2) * 8 + (lm & 3) + 2;
        #pragma unroll
        for (int kc = 0; kc < 4; kc++)
            A3[kc] = *(const f16x8*)(sXK + swz128(hrow, kc * 32 + quad * 8));
    }

    // ---- P2: K,V GEMM, stripe-synchronized in-place overwrite.
    // Iteration m: all waves read X rows [16m,16m+16) -> barrier -> write K
    // over the SAME rows. V tiles (head w) accumulate into registers.
    h2 vpk[2][4][2];
    #pragma unroll
    for (int m = 0; m < 4; m++) {
        f16x8 A[4];
        #pragma unroll
        for (int kc = 0; kc < 4; kc++)
            A[kc] = *(const f16x8*)(sXK + swz128(m * 16 + lm, kc * 32 + quad * 8));
        __syncthreads();                  // all reads of stripe m complete
        #pragma unroll
        for (int ni = 0; ni < 4; ni++) {
            f32x4 acc = {0.f, 0.f, 0.f, 0.f};
            #pragma unroll
            for (int kc = 0; kc < 4; kc++)
                acc = __builtin_amdgcn_mfma_f32_16x16x32_f16(
                    A[kc], BKV[ni][kc], acc, 0, 0, 0);
            if (ni < 2) {
                int n = w + 4 * ni;
                #pragma unroll
                for (int r = 0; r < 4; r++)
                    sXK[swz128(m * 16 + quad * 4 + r, n * 16 + lm)] = (_Float16)acc[r];
            } else {
                h2 p0, p1;
                p0[0] = (_Float16)acc[0]; p0[1] = (_Float16)acc[1];
                p1[0] = (_Float16)acc[2]; p1[1] = (_Float16)acc[3];
                vpk[ni - 2][m][0] = p0;
                vpk[ni - 2][m][1] = p1;
            }
        }
    }

    // ---- pre-issue Q weight fragments (global-only dep; in flight across B2)
    f16x8 BQ[2][4];
    #pragma unroll
    for (int nn = 0; nn < 2; nn++) {
        const _Float16* wr = wqkv + (size_t)((2 * w + nn) * 16 + lm) * 128;
        #pragma unroll
        for (int kc = 0; kc < 4; kc++)
            BQ[nn][kc] = *(const f16x8*)(wr + kc * 32 + quad * 8);
    }
    __syncthreads();                      // B2: K fully written + visible

    // ---- P3b: Q GEMM; wave w computes head w's own Q channels {2w,2w+1}
    #pragma unroll
    for (int nn = 0; nn < 2; nn++) {
        f32x4 acc = {0.f, 0.f, 0.f, 0.f};
        #pragma unroll
        for (int kc = 0; kc < 4; kc++)
            acc = __builtin_amdgcn_mfma_f32_16x16x32_f16(
                A3[kc], BQ[nn][kc], acc, 0, 0, 0);
        #pragma unroll
        for (int r = 0; r < 4; r++)
            sQ[swz128(quad * 4 + r, (2 * w + nn) * 16 + lm)] = (_Float16)acc[r];
    }

    // ---- QK^T: S[px=quad*4+r][pos=n*16+lm] fragments (same-wave sQ dep only)
    f32x4 S[4];
    {
        f16x8 Aq = *(const f16x8*)(sQ + swz128(lm, w * 32 + quad * 8));
        #pragma unroll
        for (int n = 0; n < 4; n++) {
            f16x8 Bk = *(const f16x8*)(sXK + swz128(n * 16 + lm, w * 32 + quad * 8));
            f32x4 z = {0.f, 0.f, 0.f, 0.f};
            S[n] = __builtin_amdgcn_mfma_f32_16x16x32_f16(Aq, Bk, z, 0, 0, 0);
        }
    }
    __syncthreads();                      // B2.5: all K reads done; region free

    // ---- softmax on fragments. px=(quad,r): window = hy in [quad,quad+5),
    // hx in [r,r+5). P -> swz64 head slab (lower 8KB of dead K region).
    _Float16* sPh = (_Float16*)(smem + w * 2048);          // [16 px][64 pos] swz
    float inv4[4];
    {
        const float scale = 0.17677669529663689f;
        #pragma unroll
        for (int r = 0; r < 4; r++) {
            float e[4];
            float mx = -1e30f;
            #pragma unroll
            for (int n = 0; n < 4; n++) {
                int hy = n * 2 + (lm >> 3), hx = lm & 7;
                bool memb = (hy >= quad) && (hy < quad + 5) && (hx >= r) && (hx < r + 5);
                e[n] = memb ? S[n][r] * scale : -1e30f;
                mx = fmaxf(mx, e[n]);
            }
            mx = fmaxf(mx, __shfl_xor(mx, 1));
            mx = fmaxf(mx, __shfl_xor(mx, 2));
            mx = fmaxf(mx, __shfl_xor(mx, 4));
            mx = fmaxf(mx, __shfl_xor(mx, 8));
            float sum = 0.f;
            #pragma unroll
            for (int n = 0; n < 4; n++) {
                float ev = __expf(e[n] - mx);   // masked -> exp(-huge) == 0
                e[n] = ev;
                sum += ev;
            }
            sum += __shfl_xor(sum, 1);
            sum += __shfl_xor(sum, 2);
            sum += __shfl_xor(sum, 4);
            sum += __shfl_xor(sum, 8);
            inv4[r] = 1.f / sum;
            #pragma unroll
            for (int n = 0; n < 4; n++)
                sPh[swz64(quad * 4 + r, n * 16 + lm)] = (_Float16)e[n];
        }
    }

    // ---- PV: out[px][d] = (sum_pos P*V) * inv. K=64 as 2 halves of 32 pos;
    // V^T [32 d][32 pos] staged per half into a 2KB wave slab (upper 8KB).
    // Same-wave in-order LDS: half-1 stage writes cannot pass half-0 reads.
    _Float16* sVh = (_Float16*)(smem + 8192 + w * 2048);
    _Float16* sAo = sQ;                   // overlays dead sQ
    {
        f32x4 acc2[2] = {{0.f, 0.f, 0.f, 0.f}, {0.f, 0.f, 0.f, 0.f}};
        #pragma unroll
        for (int h = 0; h < 2; h++) {
            #pragma unroll
            for (int nn = 0; nn < 2; nn++)
                #pragma unroll
                for (int mm = 0; mm < 2; mm++)
                    #pragma unroll
                    for (int rp = 0; rp < 2; rp++)
                        *(h2*)(sVh + swz32(nn * 16 + lm, mm * 16 + quad * 4 + rp * 2))
                            = vpk[nn][2 * h + mm][rp];
            f16x8 Ap = *(const f16x8*)(sPh + swz64(lm, h * 32 + quad * 8));
            #pragma unroll
            for (int nd = 0; nd < 2; nd++) {
                f16x8 Bv = *(const f16x8*)(sVh + swz32(nd * 16 + lm, quad * 8));
                acc2[nd] = __builtin_amdgcn_mfma_f32_16x16x32_f16(Ap, Bv, acc2[nd], 0, 0, 0);
            }
        }
        #pragma unroll
        for (int nd = 0; nd < 2; nd++)
            #pragma unroll
            for (int r = 0; r < 4; r++)
                sAo[swz128(quad * 4 + r, w * 32 + nd * 16 + lm)] =
                    (_Float16)(acc2[nd][r] * inv4[r]);
    }
    __syncthreads();                      // B4: sAo complete (all heads)

    // ---- proj: out[c][px] = sum_o wp[c][o] * ao[px][o].
    // Proj weight fragments loaded HERE (not held across PV): at 4.5+ blocks
    // per CU the L2-hot loads are TLP-hidden; saves 32 VGPRs during PV.
    {
        f16x8 Bf[4];
        #pragma unroll
        for (int kc = 0; kc < 4; kc++)
            Bf[kc] = *(const f16x8*)(sAo + swz128(lm, kc * 32 + quad * 8));
        int gp = (y0 + (lm >> 2)) * 96 + x0 + (lm & 3);
        #pragma unroll
        for (int mi = 0; mi < 2; mi++) {
            const _Float16* wr = wp16 + (size_t)((w * 2 + mi) * 16 + lm) * 128;
            f32x4 acc = {0.f, 0.f, 0.f, 0.f};
            #pragma unroll
            for (int kc = 0; kc < 4; kc++)
                acc = __builtin_amdgcn_mfma_f32_16x16x32_f16(
                    *(const f16x8*)(wr + kc * 32 + quad * 8), Bf[kc], acc, 0, 0, 0);
            int c0 = (w * 2 + mi) * 16 + quad * 4;
            #pragma unroll
            for (int r = 0; r < 4; r++)
                ob[(size_t)(c0 + r) * PP + gp] = acc[r];
        }
    }
}

extern "C" void kernel_launch(void* const* d_in, const int* in_sizes, int n_in,
                              void* d_out, int out_size, void* d_ws, size_t ws_size,
                              hipStream_t stream)
{
    const float* x  = (const float*)d_in[0];
    const float* wq = (const float*)d_in[1];
    const float* wk = (const float*)d_in[2];
    const float* wv = (const float*)d_in[3];
    const float* wp = (const float*)d_in[4];
    float* out = (float*)d_out;

    _Float16* wqkv16 = (_Float16*)d_ws;          // 384*128
    _Float16* wp16   = wqkv16 + 49152;           // 128*128

    prep_w<<<dim3(64), 256, 0, stream>>>(wq, wk, wv, wp, wqkv16, wp16);
    fused_attn<<<dim3(1152), 256, 0, stream>>>(x, wqkv16, wp16, out);
}

// Round 11
// 103.425 us; speedup vs baseline: 1.4794x; 1.4794x over previous
//
#include <hip/hip_runtime.h>
#include <hip/hip_fp16.h>

#define PP 9216   // 96*96 pixels per batch

typedef _Float16 f16x8 __attribute__((ext_vector_type(8)));
typedef _Float16 f16x4 __attribute__((ext_vector_type(4)));
typedef float    f32x4 __attribute__((ext_vector_type(4)));

// swizzled half-index within a 128-half (256B, 16x16B-chunk) row
__device__ __forceinline__ int swz128(int row, int hc) {
    return row * 128 + (((hc >> 3) ^ (row & 15)) << 3) + (hc & 7);
}
// swizzled half-index within a 64-half (128B, 8x16B-chunk) row
__device__ __forceinline__ int swz64(int row, int hc) {
    return row * 64 + (((hc >> 3) ^ (row & 7)) << 3) + (hc & 7);
}

__device__ __forceinline__ f16x8 zero8() {
    f16x8 z;
    #pragma unroll
    for (int e = 0; e < 8; e++) z[e] = (_Float16)0;
    return z;
}

// ---------------------------------------------------------------------------
// prep_w: one-time f32 -> f16 weight conversion.
// wqkv16[o][c], o in [0,384): 0-127 wq, 128-255 wk, 256-383 wv. wp16[c][o].
// ---------------------------------------------------------------------------
__global__ __launch_bounds__(256) void prep_w(
    const float* __restrict__ wq, const float* __restrict__ wk,
    const float* __restrict__ wv, const float* __restrict__ wp,
    _Float16* __restrict__ wqkv16, _Float16* __restrict__ wp16)
{
    int e = (blockIdx.x * 256 + threadIdx.x) * 4;   // 4 elems/thread, 65536 total
    const float* src;
    _Float16* dst;
    if (e < 49152) {
        int o = e >> 7;
        src = (o < 128) ? (wq + (size_t)o * 128)
            : (o < 256) ? (wk + (size_t)(o - 128) * 128)
                        : (wv + (size_t)(o - 256) * 128);
        src += (e & 127);
        dst = wqkv16 + e;
    } else {
        int j = e - 49152;
        src = wp + j;
        dst = wp16 + j;
    }
    float4 v = *(const float4*)src;
    f16x4 h;
    h[0] = (_Float16)v.x; h[1] = (_Float16)v.y;
    h[2] = (_Float16)v.z; h[3] = (_Float16)v.w;
    *(f16x4*)dst = h;
}

// ---------------------------------------------------------------------------
// QKV GEMM: qkv[b][p][o] = sum_c x[b][c][p] * wqkv[o][c], f16 out.
// Block 64px x 192o (grid 144,2,2), wave 32px x 96o. x staged through LDS
// with in-block transpose+cvt (coalesced f32 reads); B-frags gathered from
// L2-hot f16 weights; R0's proven LDS epilogue for coalesced 16B stores.
// One barrier.
// ---------------------------------------------------------------------------
__global__ __launch_bounds__(256) void qkv_gemm(
    const float* __restrict__ x, const _Float16* __restrict__ wqkv,
    _Float16* __restrict__ qkvout)
{
    __shared__ __align__(16) char smem[43008];
    _Float16* sX   = (_Float16*)smem;               // [64 px][128 c] swz128, 16KB
    _Float16* sEpi = (_Float16*)(smem + 16384);     // 4 wave strips [32][104]

    const int t = threadIdx.x;
    const int w = t >> 6, lane = t & 63, lm = lane & 15, quad = lane >> 4;
    const int b = blockIdx.z;
    const int p0 = blockIdx.x * 64;
    const int nbase = blockIdx.y * 192;

    const float* xb = x + (size_t)b * 128 * PP;
    _Float16* qout = qkvout + (size_t)b * PP * 384;

    // stage x tile: lane==px coalesced f32 reads, transposed f16 LDS writes
    {
        const int px = t & 63;
        const int c0 = (t >> 6) * 32;
        #pragma unroll
        for (int i = 0; i < 32; i++) {
            float v = xb[(size_t)(c0 + i) * PP + p0 + px];
            sX[swz128(px, c0 + i)] = (_Float16)v;
        }
    }
    __syncthreads();

    const int ms0 = (w & 1) * 32;
    const int nw = (w >> 1) * 96;

    f16x8 A[2][4];
    #pragma unroll
    for (int ms = 0; ms < 2; ms++)
        #pragma unroll
        for (int kc = 0; kc < 4; kc++)
            A[ms][kc] = *(const f16x8*)(sX + swz128(ms0 + ms * 16 + lm, kc * 32 + quad * 8));

    _Float16* strip = sEpi + w * 3328;   // [32 rows][104]
    #pragma unroll
    for (int nt = 0; nt < 6; nt++) {
        const int o = nbase + nw + nt * 16 + lm;
        const _Float16* wr = wqkv + (size_t)o * 128;
        f16x8 Bf[4];
        #pragma unroll
        for (int kc = 0; kc < 4; kc++)
            Bf[kc] = *(const f16x8*)(wr + kc * 32 + quad * 8);
        #pragma unroll
        for (int ms = 0; ms < 2; ms++) {
            f32x4 acc = {0.f, 0.f, 0.f, 0.f};
            #pragma unroll
            for (int kc = 0; kc < 4; kc++)
                acc = __builtin_amdgcn_mfma_f32_16x16x32_f16(A[ms][kc], Bf[kc], acc, 0, 0, 0);
            #pragma unroll
            for (int r = 0; r < 4; r++)
                strip[(ms * 16 + quad * 4 + r) * 104 + nt * 16 + lm] = (_Float16)acc[r];
        }
    }

    // wave-local epilogue: 32 rows x 96 halfs -> coalesced 16B stores
    #pragma unroll
    for (int it = 0; it < 6; it++) {
        int idx = it * 64 + lane;      // 0..383
        int row = idx / 12;            // 0..31
        int ch  = idx % 12;            // 16B chunk within row
        uint4 v = *(const uint4*)&strip[row * 104 + ch * 8];
        *(uint4*)(qout + (size_t)(p0 + ms0 + row) * 384 + nbase + nw + ch * 8) = v;
    }
}

// ---------------------------------------------------------------------------
// Fused attention+proj. One block per (4x4 tile, batch); wave w = head w.
// Q/K MFMA fragments gathered directly from global qkv (L2-hot, halo shared
// across blocks; OOB -> zero frag == reference zero-padding). V gathered and
// transposed into a 4KB wave-local LDS slab. Register softmax (R6 path).
// ONE barrier (before proj). 28KB LDS -> 5 blocks/CU; launch_bounds(256,4)
// -> 64-VGPR cap (proven no-spill operating point).
// ---------------------------------------------------------------------------
__global__ __launch_bounds__(256, 4) void attn_fused(
    const _Float16* __restrict__ qkv, const _Float16* __restrict__ wp16,
    float* __restrict__ out)
{
    __shared__ __align__(16) char smem[28672];
    const int t = threadIdx.x;
    const int w = t >> 6, lane = t & 63, lm = lane & 15, quad = lane >> 4;

    // XCD-bijective swizzle: 1152 = 8 XCDs x 144 contiguous blocks
    const int wgid = (blockIdx.x & 7) * 144 + (blockIdx.x >> 3);
    const int b = wgid / 576;
    const int rem = wgid - b * 576;
    const int x0 = (rem % 24) * 4, y0 = (rem / 24) * 4;

    const _Float16* qb = qkv + (size_t)b * PP * 384;
    float* ob = out + (size_t)b * 128 * PP;

    _Float16* sVT = (_Float16*)(smem + w * 6144);          // [32 d][64 pos] swz64
    _Float16* sPh = (_Float16*)(smem + w * 6144 + 4096);   // [16 px][64 pos] swz64
    _Float16* sAo = (_Float16*)(smem + 24576);             // [16 px][128 o] swz128

    // ---- stage V^T for head w: lane = pos; gather 64B, write transposed.
    {
        const int pos = lane;
        const int gy = y0 - 2 + (pos >> 3), gx = x0 - 2 + (pos & 7);
        const bool valid = ((unsigned)gy < 96u) && ((unsigned)gx < 96u);
        const int gp = valid ? (gy * 96 + gx) : 0;
        const _Float16* vsrc = qb + (size_t)gp * 384 + 256 + w * 32;
        f16x8 vv[4];
        #pragma unroll
        for (int j = 0; j < 4; j++) {
            f16x8 ld = *(const f16x8*)(vsrc + j * 8);
            vv[j] = valid ? ld : zero8();
        }
        #pragma unroll
        for (int j = 0; j < 4; j++)
            #pragma unroll
            for (int e = 0; e < 8; e++) {
                int d = j * 8 + e;
                sVT[d * 64 + ((((pos >> 3)) ^ (d & 7)) << 3) + (pos & 7)] = vv[j][e];
            }
    }

    // ---- Q A-frag: lane (lm,quad) holds Q[px=lm][d=quad*8..+8]
    const int gpq = (y0 + (lm >> 2)) * 96 + x0 + (lm & 3);
    f16x8 Aq = *(const f16x8*)(qb + (size_t)gpq * 384 + w * 32 + quad * 8);

    // ---- QK^T: K B-frags gathered directly from global; OOB pos -> 0 rows
    f32x4 S[4];
    #pragma unroll
    for (int n = 0; n < 4; n++) {
        int pos = n * 16 + lm;
        int gy = y0 - 2 + (pos >> 3), gx = x0 - 2 + (pos & 7);
        bool valid = ((unsigned)gy < 96u) && ((unsigned)gx < 96u);
        int gp = valid ? (gy * 96 + gx) : 0;
        f16x8 ld = *(const f16x8*)(qb + (size_t)gp * 384 + 128 + w * 32 + quad * 8);
        f16x8 Bk = valid ? ld : zero8();
        f32x4 z = {0.f, 0.f, 0.f, 0.f};
        S[n] = __builtin_amdgcn_mfma_f32_16x16x32_f16(Aq, Bk, z, 0, 0, 0);
    }

    // ---- softmax on fragments (R6-proven). px=(quad,r): window hy in
    // [quad,quad+5), hx in [r,r+5). Reduce in-lane + shfl over 16-lane group.
    float inv4[4];
    {
        const float scale = 0.17677669529663689f;
        #pragma unroll
        for (int r = 0; r < 4; r++) {
            float e[4];
            float mx = -1e30f;
            #pragma unroll
            for (int n = 0; n < 4; n++) {
                int hy = n * 2 + (lm >> 3), hx = lm & 7;
                bool memb = (hy >= quad) && (hy < quad + 5) && (hx >= r) && (hx < r + 5);
                e[n] = memb ? S[n][r] * scale : -1e30f;
                mx = fmaxf(mx, e[n]);
            }
            mx = fmaxf(mx, __shfl_xor(mx, 1));
            mx = fmaxf(mx, __shfl_xor(mx, 2));
            mx = fmaxf(mx, __shfl_xor(mx, 4));
            mx = fmaxf(mx, __shfl_xor(mx, 8));
            float sum = 0.f;
            #pragma unroll
            for (int n = 0; n < 4; n++) {
                float ev = __expf(e[n] - mx);   // masked -> exp(-huge) == 0
                e[n] = ev;
                sum += ev;
            }
            sum += __shfl_xor(sum, 1);
            sum += __shfl_xor(sum, 2);
            sum += __shfl_xor(sum, 4);
            sum += __shfl_xor(sum, 8);
            inv4[r] = 1.f / sum;
            #pragma unroll
            for (int n = 0; n < 4; n++)
                sPh[swz64(quad * 4 + r, n * 16 + lm)] = (_Float16)e[n];
        }
    }

    // ---- PV: out[px][d] = (sum_pos P*V) * inv  (all wave-local LDS deps)
    {
        f32x4 acc2[2] = {{0.f, 0.f, 0.f, 0.f}, {0.f, 0.f, 0.f, 0.f}};
        #pragma unroll
        for (int kc = 0; kc < 2; kc++) {
            f16x8 Ap = *(const f16x8*)(sPh + swz64(lm, kc * 32 + quad * 8));
            #pragma unroll
            for (int nd = 0; nd < 2; nd++) {
                int row = nd * 16 + lm;          // d
                int hc = kc * 32 + quad * 8;     // pos chunk
                f16x8 Bv = *(const f16x8*)(sVT + row * 64
                               + (((hc >> 3) ^ (row & 7)) << 3) + (hc & 7));
                acc2[nd] = __builtin_amdgcn_mfma_f32_16x16x32_f16(Ap, Bv, acc2[nd], 0, 0, 0);
            }
        }
        #pragma unroll
        for (int nd = 0; nd < 2; nd++)
            #pragma unroll
            for (int r = 0; r < 4; r++)
                sAo[swz128(quad * 4 + r, w * 32 + nd * 16 + lm)] =
                    (_Float16)(acc2[nd][r] * inv4[r]);
    }
    __syncthreads();                      // the ONE barrier: sAo complete

    // ---- proj: out[c][px] = sum_o wp[c][o] * ao[px][o]
    {
        f16x8 Bf[4];
        #pragma unroll
        for (int kc = 0; kc < 4; kc++)
            Bf[kc] = *(const f16x8*)(sAo + swz128(lm, kc * 32 + quad * 8));
        int gp = (y0 + (lm >> 2)) * 96 + x0 + (lm & 3);
        #pragma unroll
        for (int mi = 0; mi < 2; mi++) {
            const _Float16* wr = wp16 + (size_t)((w * 2 + mi) * 16 + lm) * 128;
            f32x4 acc = {0.f, 0.f, 0.f, 0.f};
            #pragma unroll
            for (int kc = 0; kc < 4; kc++)
                acc = __builtin_amdgcn_mfma_f32_16x16x32_f16(
                    *(const f16x8*)(wr + kc * 32 + quad * 8), Bf[kc], acc, 0, 0, 0);
            int c0 = (w * 2 + mi) * 16 + quad * 4;
            #pragma unroll
            for (int r = 0; r < 4; r++)
                ob[(size_t)(c0 + r) * PP + gp] = acc[r];
        }
    }
}

extern "C" void kernel_launch(void* const* d_in, const int* in_sizes, int n_in,
                              void* d_out, int out_size, void* d_ws, size_t ws_size,
                              hipStream_t stream)
{
    const float* x  = (const float*)d_in[0];
    const float* wq = (const float*)d_in[1];
    const float* wk = (const float*)d_in[2];
    const float* wv = (const float*)d_in[3];
    const float* wp = (const float*)d_in[4];
    float* out = (float*)d_out;

    _Float16* wqkv16 = (_Float16*)d_ws;          // 384*128
    _Float16* wp16   = wqkv16 + 49152;           // 128*128
    _Float16* qkvh   = wp16 + 16384;             // 2*9216*384

    prep_w<<<dim3(64), 256, 0, stream>>>(wq, wk, wv, wp, wqkv16, wp16);
    qkv_gemm<<<dim3(144, 2, 2), 256, 0, stream>>>(x, wqkv16, qkvh);
    attn_fused<<<dim3(1152), 256, 0, stream>>>(qkvh, wp16, out);
}